// Round 2
// baseline (1129.260 us; speedup 1.0000x reference)
//
#include <hip/hip_runtime.h>
#include <cstddef>
#include <cstdint>

// Stacked SimpleRNN, fp32.  B=512, T=512, F=78, hiddens 16/32/64/70, dense->5+softmax.
// Structure: proj (batched GEMM xw = in @ W + b over M=B*T rows) alternating with
// rec (sequential scan over T; U held in VGPRs per-lane; h double-buffered in LDS).

#define BB 512
#define TT 512
#define M_TOTAL (BB * TT)

__device__ __forceinline__ float tanh_fast(float x) {
  // tanh(x) = sign(x) * (1 - 2/(e^{2|x|}+1)); exp overflow -> inf -> result 1. Accurate to ~1e-7.
  float ax = fabsf(x);
  float e = __expf(ax + ax);
  float r = 1.0f - 2.0f / (e + 1.0f);
  return (x >= 0.0f) ? r : -r;
}

__device__ __forceinline__ void fma4(float4& a, float s, const float4 w) {
  a.x = fmaf(s, w.x, a.x);
  a.y = fmaf(s, w.y, a.y);
  a.z = fmaf(s, w.z, a.z);
  a.w = fmaf(s, w.w, a.w);
}

// out[M,N] = in[M,K] @ W[K,N] + b.  Block 256 threads; each active thread computes a
// 4-row x 4-col tile. W and bias staged in LDS (cols padded to NP=4*CG, zeros).
template<int K, int N, int CG>
__global__ __launch_bounds__(256)
void proj_kernel(const float* __restrict__ in, const float* __restrict__ W,
                 const float* __restrict__ bias, float* __restrict__ out, int M)
{
  constexpr int NP = CG * 4;
  constexpr int RG = 256 / CG;  // active row-groups
  __shared__ __align__(16) float wlds[K][NP];
  __shared__ __align__(16) float blds[NP];
  const int tid = threadIdx.x;
  for (int idx = tid; idx < K * NP; idx += 256) {
    int k = idx / NP, jj = idx - k * NP;
    wlds[k][jj] = (jj < N) ? W[k * N + jj] : 0.0f;
  }
  if (tid < NP) blds[tid] = (tid < N) ? bias[tid] : 0.0f;
  __syncthreads();

  const int c = tid % CG;
  const int rg = tid / CG;
  if (rg >= RG) return;  // no barriers after this point
  const int j0 = c * 4;
  const long row0 = (long)blockIdx.x * (RG * 4) + (long)rg * 4;

  float4 b4 = *reinterpret_cast<const float4*>(&blds[j0]);
  float4 acc[4] = {b4, b4, b4, b4};
  const float* inp[4];
  bool rv[4];
  #pragma unroll
  for (int rr = 0; rr < 4; ++rr) {
    long rowi = row0 + rr;
    rv[rr] = rowi < M;
    inp[rr] = in + (rv[rr] ? rowi : 0) * (long)K;
  }

  int k = 0;
  for (; k + 4 <= K; k += 4) {
    float4 w0 = *reinterpret_cast<const float4*>(&wlds[k + 0][j0]);
    float4 w1 = *reinterpret_cast<const float4*>(&wlds[k + 1][j0]);
    float4 w2 = *reinterpret_cast<const float4*>(&wlds[k + 2][j0]);
    float4 w3 = *reinterpret_cast<const float4*>(&wlds[k + 3][j0]);
    #pragma unroll
    for (int rr = 0; rr < 4; ++rr) {
      // float2 pairs: all row strides (78,16,32,64) are even -> 8B-aligned at even k
      float2 i0 = *reinterpret_cast<const float2*>(inp[rr] + k);
      float2 i1 = *reinterpret_cast<const float2*>(inp[rr] + k + 2);
      fma4(acc[rr], i0.x, w0);
      fma4(acc[rr], i0.y, w1);
      fma4(acc[rr], i1.x, w2);
      fma4(acc[rr], i1.y, w3);
    }
  }
  for (; k < K; ++k) {  // K tail (K=78)
    float4 w0 = *reinterpret_cast<const float4*>(&wlds[k][j0]);
    #pragma unroll
    for (int rr = 0; rr < 4; ++rr) fma4(acc[rr], inp[rr][k], w0);
  }

  #pragma unroll
  for (int rr = 0; rr < 4; ++rr) {
    if (!rv[rr]) continue;
    long obase = (row0 + rr) * (long)N + j0;
    if constexpr ((N % 4) == 0) {
      *reinterpret_cast<float4*>(&out[obase]) = acc[rr];
    } else {
      if (j0 + 4 <= N) {
        *reinterpret_cast<float2*>(&out[obase]) = make_float2(acc[rr].x, acc[rr].y);
        *reinterpret_cast<float2*>(&out[obase + 2]) = make_float2(acc[rr].z, acc[rr].w);
      } else {
        float v[4] = {acc[rr].x, acc[rr].y, acc[rr].z, acc[rr].w};
        #pragma unroll
        for (int jj = 0; jj < 4; ++jj)
          if (j0 + jj < N) out[obase + jj] = v[jj];
      }
    }
  }
}

// Recurrence: h_t = tanh(xw[:,t,:] + h_{t-1} @ U).  Lane (r = tid/H rows-in-block,
// j = tid%H column).  U[:,j] in VGPRs.  h double-buffered in LDS, one barrier/step.
// xw streamed with depth-2 prefetch.  If LAST: keep only final h, fuse dense+softmax.
template<int H, int ROWS, int BLK, bool LAST>
__global__ __launch_bounds__(BLK)
void rec_kernel(const float* __restrict__ xw, const float* __restrict__ U,
                float* __restrict__ hseq,
                const float* __restrict__ Wd, const float* __restrict__ bd,
                float* __restrict__ outp)
{
  constexpr int HP = (H + 3) & ~3;  // pad for float4 LDS reads; pad entries stay 0
  const int tid = threadIdx.x;
  const int r = tid / H;
  const int j = tid - r * H;
  const bool active = (r < ROWS);
  const int rc = active ? r : 0;
  int row = blockIdx.x * ROWS + r;
  if (row >= BB) row = BB - 1;  // clamp so inactive lanes load valid addresses

  __shared__ __align__(16) float hbuf[2][ROWS][HP];
  __shared__ float slog[8];
  for (int i = tid; i < 2 * ROWS * HP; i += BLK)
    reinterpret_cast<float*>(hbuf)[i] = 0.0f;

  float u[HP];
  #pragma unroll
  for (int kk = 0; kk < HP; ++kk)
    u[kk] = (kk < H && active) ? U[kk * H + j] : 0.0f;

  const float* xwrow = xw + ((size_t)row * TT) * H + j;
  float* hout = hseq + ((size_t)row * TT) * H + j;  // valid dummy buffer when LAST
  __syncthreads();

  float p0 = xwrow[0];        // t = 0
  float p1 = xwrow[H];        // t = 1
  for (int t = 0; t < TT; ++t) {
    float xv = p0;
    p0 = p1;
    int tn = (t + 2 < TT) ? (t + 2) : (TT - 1);
    p1 = xwrow[(size_t)tn * H];  // prefetch depth 2

    const float* hb = &hbuf[t & 1][rc][0];
    float a0 = xv, a1 = 0.0f, a2 = 0.0f, a3 = 0.0f;
    #pragma unroll
    for (int k4 = 0; k4 < HP / 4; ++k4) {  // broadcast LDS reads; 4 split accumulators
      float4 h4 = *reinterpret_cast<const float4*>(hb + 4 * k4);
      a0 = fmaf(h4.x, u[4 * k4 + 0], a0);
      a1 = fmaf(h4.y, u[4 * k4 + 1], a1);
      a2 = fmaf(h4.z, u[4 * k4 + 2], a2);
      a3 = fmaf(h4.w, u[4 * k4 + 3], a3);
    }
    float hn = tanh_fast((a0 + a1) + (a2 + a3));
    if (active) {
      hbuf[(t & 1) ^ 1][r][j] = hn;
      if constexpr (!LAST) hout[(size_t)t * H] = hn;
    }
    __syncthreads();
  }

  if constexpr (LAST) {
    // final h is in hbuf[0][0][*] (t=511 wrote buffer 0).  Dense (70->5) + softmax.
    if (tid < 5) {
      float l = bd[tid];
      #pragma unroll
      for (int kk = 0; kk < H; ++kk)
        l = fmaf(hbuf[0][0][kk], Wd[kk * 5 + tid], l);
      slog[tid] = l;
    }
    __syncthreads();
    if (tid < 5) {
      float m = slog[0];
      #pragma unroll
      for (int i = 1; i < 5; ++i) m = fmaxf(m, slog[i]);
      float s = 0.0f;
      #pragma unroll
      for (int i = 0; i < 5; ++i) s += __expf(slog[i] - m);
      outp[(size_t)blockIdx.x * 5 + tid] = __expf(slog[tid] - m) / s;
    }
  }
}

extern "C" void kernel_launch(void* const* d_in, const int* in_sizes, int n_in,
                              void* d_out, int out_size, void* d_ws, size_t ws_size,
                              hipStream_t stream)
{
  const float* x  = (const float*)d_in[0];
  const float* W0 = (const float*)d_in[1];
  const float* U0 = (const float*)d_in[2];
  const float* b0 = (const float*)d_in[3];
  const float* W1 = (const float*)d_in[4];
  const float* U1 = (const float*)d_in[5];
  const float* b1 = (const float*)d_in[6];
  const float* W2 = (const float*)d_in[7];
  const float* U2 = (const float*)d_in[8];
  const float* b2 = (const float*)d_in[9];
  const float* W3 = (const float*)d_in[10];
  const float* U3 = (const float*)d_in[11];
  const float* b3 = (const float*)d_in[12];
  const float* Wd = (const float*)d_in[13];
  const float* bd = (const float*)d_in[14];
  float* outp = (float*)d_out;

  // ws ping-pong: A holds xw0/xw1/xw2/xw3 (max 73,400,320 B), Bv holds h0/h1/h2 (max 67,108,864 B)
  float* A  = (float*)d_ws;
  float* Bv = (float*)((char*)d_ws + 73400320);

  const int M = M_TOTAL;

  // xw0 = x @ W0 + b0                    [M,78]x[78,16]
  proj_kernel<78, 16, 4><<<M / 256, 256, 0, stream>>>(x, W0, b0, A, M);
  // h0 sequence                          scan H=16, 4 rows/block (1 wave)
  rec_kernel<16, 4, 64, false><<<BB / 4, 64, 0, stream>>>(A, U0, Bv, Wd, bd, outp);
  // xw1 = h0 @ W1 + b1                   [M,16]x[16,32]
  proj_kernel<16, 32, 8><<<M / 128, 256, 0, stream>>>(Bv, W1, b1, A, M);
  // h1                                   H=32, 2 rows/block
  rec_kernel<32, 2, 64, false><<<BB / 2, 64, 0, stream>>>(A, U1, Bv, Wd, bd, outp);
  // xw2 = h1 @ W2 + b2                   [M,32]x[32,64]
  proj_kernel<32, 64, 16><<<M / 64, 256, 0, stream>>>(Bv, W2, b2, A, M);
  // h2                                   H=64, 1 row/block
  rec_kernel<64, 1, 64, false><<<BB, 64, 0, stream>>>(A, U2, Bv, Wd, bd, outp);
  // xw3 = h2 @ W3 + b3                   [M,64]x[64,70]
  proj_kernel<64, 70, 18><<<(M + 55) / 56, 256, 0, stream>>>(Bv, W3, b3, A, M);
  // final scan H=70 (2 waves) + dense + softmax; hseq arg is a valid dummy (unused)
  rec_kernel<70, 1, 128, true><<<BB, 128, 0, stream>>>(A, U3, Bv, Wd, bd, outp);
}

// Round 3
// 1123.117 us; speedup vs baseline: 1.0055x; 1.0055x over previous
//
#include <hip/hip_runtime.h>
#include <cstddef>
#include <cstdint>

// Stacked SimpleRNN, fp32.  B=512, T=512, F=78, hiddens 16/32/64/70, dense->5+softmax.
// proj = batched GEMM xw = in @ W + b over M=B*T rows; rec = sequential scan over T.
// rec: U in VGPRs (launch_bounds(.,1) -> no scratch), h double-buffered in LDS,
// per-step sync via raw "s_waitcnt lgkmcnt(0); s_barrier" (NO vmcnt drain -> xw
// prefetch + hseq stores stay in flight across steps; the implicit vmcnt(0) of
// __syncthreads was costing ~900 cyc/step in round 2).

#define BB 512
#define TT 512
#define M_TOTAL (BB * TT)

// LDS-visibility sync WITHOUT the compiler's vmcnt(0) drain.
#define LDS_BARRIER() asm volatile("s_waitcnt lgkmcnt(0)\n\ts_barrier" ::: "memory")

__device__ __forceinline__ float tanh_fast(float x) {
  // tanh(x) = sign(x) * (1 - 2/(e^{2|x|}+1)); exp overflow -> inf -> result 1.
  float ax = fabsf(x);
  float e = __expf(ax + ax);
  float r = 1.0f - 2.0f / (e + 1.0f);
  return (x >= 0.0f) ? r : -r;
}

__device__ __forceinline__ void fma4(float4& a, float s, const float4 w) {
  a.x = fmaf(s, w.x, a.x);
  a.y = fmaf(s, w.y, a.y);
  a.z = fmaf(s, w.z, a.z);
  a.w = fmaf(s, w.w, a.w);
}

// out[M,N] = in[M,K] @ W[K,N] + b.  Block 256 threads; each active thread computes a
// 4-row x 4-col tile. W and bias staged in LDS (cols padded to NP=4*CG, zeros).
template<int K, int N, int CG>
__global__ __launch_bounds__(256)
void proj_kernel(const float* __restrict__ in, const float* __restrict__ W,
                 const float* __restrict__ bias, float* __restrict__ out, int M)
{
  constexpr int NP = CG * 4;
  constexpr int RG = 256 / CG;  // active row-groups
  __shared__ __align__(16) float wlds[K][NP];
  __shared__ __align__(16) float blds[NP];
  const int tid = threadIdx.x;
  for (int idx = tid; idx < K * NP; idx += 256) {
    int k = idx / NP, jj = idx - k * NP;
    wlds[k][jj] = (jj < N) ? W[k * N + jj] : 0.0f;
  }
  if (tid < NP) blds[tid] = (tid < N) ? bias[tid] : 0.0f;
  __syncthreads();

  const int c = tid % CG;
  const int rg = tid / CG;
  if (rg >= RG) return;  // no barriers after this point
  const int j0 = c * 4;
  const long row0 = (long)blockIdx.x * (RG * 4) + (long)rg * 4;

  float4 b4 = *reinterpret_cast<const float4*>(&blds[j0]);
  float4 acc[4] = {b4, b4, b4, b4};
  const float* inp[4];
  bool rv[4];
  #pragma unroll
  for (int rr = 0; rr < 4; ++rr) {
    long rowi = row0 + rr;
    rv[rr] = rowi < M;
    inp[rr] = in + (rv[rr] ? rowi : 0) * (long)K;
  }

  int k = 0;
  for (; k + 4 <= K; k += 4) {
    float4 w0 = *reinterpret_cast<const float4*>(&wlds[k + 0][j0]);
    float4 w1 = *reinterpret_cast<const float4*>(&wlds[k + 1][j0]);
    float4 w2 = *reinterpret_cast<const float4*>(&wlds[k + 2][j0]);
    float4 w3 = *reinterpret_cast<const float4*>(&wlds[k + 3][j0]);
    #pragma unroll
    for (int rr = 0; rr < 4; ++rr) {
      float2 i0 = *reinterpret_cast<const float2*>(inp[rr] + k);
      float2 i1 = *reinterpret_cast<const float2*>(inp[rr] + k + 2);
      fma4(acc[rr], i0.x, w0);
      fma4(acc[rr], i0.y, w1);
      fma4(acc[rr], i1.x, w2);
      fma4(acc[rr], i1.y, w3);
    }
  }
  for (; k < K; ++k) {  // K tail (K=78)
    float4 w0 = *reinterpret_cast<const float4*>(&wlds[k][j0]);
    #pragma unroll
    for (int rr = 0; rr < 4; ++rr) fma4(acc[rr], inp[rr][k], w0);
  }

  #pragma unroll
  for (int rr = 0; rr < 4; ++rr) {
    if (!rv[rr]) continue;
    long obase = (row0 + rr) * (long)N + j0;
    if constexpr ((N % 4) == 0) {
      *reinterpret_cast<float4*>(&out[obase]) = acc[rr];
    } else {
      if (j0 + 4 <= N) {
        *reinterpret_cast<float2*>(&out[obase]) = make_float2(acc[rr].x, acc[rr].y);
        *reinterpret_cast<float2*>(&out[obase + 2]) = make_float2(acc[rr].z, acc[rr].w);
      } else {
        float v[4] = {acc[rr].x, acc[rr].y, acc[rr].z, acc[rr].w};
        #pragma unroll
        for (int jj = 0; jj < 4; ++jj)
          if (j0 + jj < N) out[obase + jj] = v[jj];
      }
    }
  }
}

// Recurrence: h_t = tanh(xw[:,t,:] + h_{t-1} @ U).  Lane (r = tid/H row-in-block,
// j = tid%H column).  U[:,j] in VGPRs (launch_bounds min-waves=1 gives the RA the
// full budget; round-2's default heuristic spilled u[] to scratch at VGPR=60).
// h double-buffered in LDS; per-step LDS_BARRIER keeps vmem in flight.
// xw streamed with depth-4 prefetch.  If LAST: fuse dense+softmax on final h.
template<int H, int ROWS, int BLK, bool LAST>
__global__ __launch_bounds__(BLK, 1)
void rec_kernel(const float* __restrict__ xw, const float* __restrict__ U,
                float* __restrict__ hseq,
                const float* __restrict__ Wd, const float* __restrict__ bd,
                float* __restrict__ outp)
{
  constexpr int HP = (H + 3) & ~3;  // pad for float4 LDS reads; pad entries stay 0
  const int tid = threadIdx.x;
  const int r = tid / H;
  const int j = tid - r * H;
  const bool active = (r < ROWS);
  const int rc = active ? r : 0;
  int row = blockIdx.x * ROWS + r;
  if (row >= BB) row = BB - 1;  // clamp so inactive lanes load valid addresses

  __shared__ __align__(16) float hbuf[2][ROWS][HP];
  __shared__ float slog[8];
  for (int i = tid; i < 2 * ROWS * HP; i += BLK)
    reinterpret_cast<float*>(hbuf)[i] = 0.0f;

  float u[HP];
  #pragma unroll
  for (int kk = 0; kk < HP; ++kk)
    u[kk] = (kk < H && active) ? U[kk * H + j] : 0.0f;

  const float* xwrow = xw + ((size_t)row * TT) * H + j;
  float* hout = hseq + ((size_t)row * TT) * H + j;  // valid dummy buffer when LAST
  __syncthreads();  // once, outside the loop

  float p0 = xwrow[0];
  float p1 = xwrow[(size_t)1 * H];
  float p2 = xwrow[(size_t)2 * H];
  float p3 = xwrow[(size_t)3 * H];
  for (int t = 0; t < TT; ++t) {
    float xv = p0;
    p0 = p1; p1 = p2; p2 = p3;
    int tn = (t + 4 < TT) ? (t + 4) : (TT - 1);
    p3 = xwrow[(size_t)tn * H];  // prefetch depth 4 (~4 steps of latency cover)

    const float* hb = &hbuf[t & 1][rc][0];
    float a0 = xv, a1 = 0.0f, a2 = 0.0f, a3 = 0.0f;
    #pragma unroll
    for (int k4 = 0; k4 < HP / 4; ++k4) {  // broadcast LDS reads; 4 split accumulators
      float4 h4 = *reinterpret_cast<const float4*>(hb + 4 * k4);
      a0 = fmaf(h4.x, u[4 * k4 + 0], a0);
      a1 = fmaf(h4.y, u[4 * k4 + 1], a1);
      a2 = fmaf(h4.z, u[4 * k4 + 2], a2);
      a3 = fmaf(h4.w, u[4 * k4 + 3], a3);
    }
    float hn = tanh_fast((a0 + a1) + (a2 + a3));
    if (active) {
      hbuf[(t & 1) ^ 1][r][j] = hn;
      if constexpr (!LAST) hout[(size_t)t * H] = hn;
    }
    LDS_BARRIER();  // lgkmcnt(0)+s_barrier only: no vmcnt drain, prefetch survives
  }

  if constexpr (LAST) {
    // final h is in hbuf[0][0][*] (t=511 wrote buffer 0).  Dense (70->5) + softmax.
    if (tid < 5) {
      float l = bd[tid];
      #pragma unroll
      for (int kk = 0; kk < H; ++kk)
        l = fmaf(hbuf[0][0][kk], Wd[kk * 5 + tid], l);
      slog[tid] = l;
    }
    __syncthreads();
    if (tid < 5) {
      float m = slog[0];
      #pragma unroll
      for (int i = 1; i < 5; ++i) m = fmaxf(m, slog[i]);
      float s = 0.0f;
      #pragma unroll
      for (int i = 0; i < 5; ++i) s += __expf(slog[i] - m);
      outp[(size_t)blockIdx.x * 5 + tid] = __expf(slog[tid] - m) / s;
    }
  }
}

extern "C" void kernel_launch(void* const* d_in, const int* in_sizes, int n_in,
                              void* d_out, int out_size, void* d_ws, size_t ws_size,
                              hipStream_t stream)
{
  const float* x  = (const float*)d_in[0];
  const float* W0 = (const float*)d_in[1];
  const float* U0 = (const float*)d_in[2];
  const float* b0 = (const float*)d_in[3];
  const float* W1 = (const float*)d_in[4];
  const float* U1 = (const float*)d_in[5];
  const float* b1 = (const float*)d_in[6];
  const float* W2 = (const float*)d_in[7];
  const float* U2 = (const float*)d_in[8];
  const float* b2 = (const float*)d_in[9];
  const float* W3 = (const float*)d_in[10];
  const float* U3 = (const float*)d_in[11];
  const float* b3 = (const float*)d_in[12];
  const float* Wd = (const float*)d_in[13];
  const float* bd = (const float*)d_in[14];
  float* outp = (float*)d_out;

  // ws ping-pong: A holds xw (max 73,400,320 B), Bv holds h sequences (max 67,108,864 B)
  float* A  = (float*)d_ws;
  float* Bv = (float*)((char*)d_ws + 73400320);

  const int M = M_TOTAL;

  // xw0 = x @ W0 + b0                    [M,78]x[78,16]
  proj_kernel<78, 16, 4><<<M / 256, 256, 0, stream>>>(x, W0, b0, A, M);
  // h0 sequence                          scan H=16, 4 rows/block (1 wave)
  rec_kernel<16, 4, 64, false><<<BB / 4, 64, 0, stream>>>(A, U0, Bv, Wd, bd, outp);
  // xw1 = h0 @ W1 + b1                   [M,16]x[16,32]
  proj_kernel<16, 32, 8><<<M / 128, 256, 0, stream>>>(Bv, W1, b1, A, M);
  // h1                                   H=32, 2 rows/block
  rec_kernel<32, 2, 64, false><<<BB / 2, 64, 0, stream>>>(A, U1, Bv, Wd, bd, outp);
  // xw2 = h1 @ W2 + b2                   [M,32]x[32,64]
  proj_kernel<32, 64, 16><<<M / 64, 256, 0, stream>>>(Bv, W2, b2, A, M);
  // h2                                   H=64, 1 row/block
  rec_kernel<64, 1, 64, false><<<BB, 64, 0, stream>>>(A, U2, Bv, Wd, bd, outp);
  // xw3 = h2 @ W3 + b3                   [M,64]x[64,70]
  proj_kernel<64, 70, 18><<<(M + 55) / 56, 256, 0, stream>>>(Bv, W3, b3, A, M);
  // final scan H=70 (2 waves) + dense + softmax; hseq arg is a valid dummy (unused)
  rec_kernel<70, 1, 128, true><<<BB, 128, 0, stream>>>(A, U3, Bv, Wd, bd, outp);
}

// Round 4
// 962.198 us; speedup vs baseline: 1.1736x; 1.1672x over previous
//
#include <hip/hip_runtime.h>
#include <cstddef>
#include <cstdint>

// Stacked SimpleRNN, fp32.  B=512, T=512, F=78, hiddens 16/32/64/70, dense->5+softmax.
// proj = batched GEMM xw = in @ W + b over M=B*T rows; rec = sequential scan over T.
//
// rec design (round 4): every rec block is a SINGLE wave (64 lanes) -> no barriers
// in the scan loop.  U[:,j] pinned in VGPRs via asm.  h lives in a tiny LDS buffer
// (broadcast ds_read_b128), written back per step; within-wave LDS RAW is in-order.
// xw is streamed with a TRUE depth-8 prefetch: t-loop unrolled x8, pf[d] reloaded
// for t+8 at compile-time index d -> vmcnt wait lands 8 steps (~1500 cyc) after
// issue.  (Rounds 2/3 had a rotating-scalar pipeline whose shift used the newest
// load every step -> effective depth 1 -> ~1450 cyc/step of pure latency, H-
// independent, which matched the observed 309 us for ALL rec sizes.)

#define BB 512
#define TT 512
#define M_TOTAL (BB * TT)

__device__ __forceinline__ float tanh_fast(float x) {
  // tanh(x) = sign(x) * (1 - 2/(e^{2|x|}+1)); exp overflow -> inf -> result 1.
  float ax = fabsf(x);
  float e = __expf(ax + ax);
  float r = 1.0f - 2.0f / (e + 1.0f);
  return (x >= 0.0f) ? r : -r;
}

__device__ __forceinline__ void fma4(float4& a, float s, const float4 w) {
  a.x = fmaf(s, w.x, a.x);
  a.y = fmaf(s, w.y, a.y);
  a.z = fmaf(s, w.z, a.z);
  a.w = fmaf(s, w.w, a.w);
}

// ---------------------------------------------------------------------------
// proj: out[M,N] = in[M,K] @ W[K,N] + b.  256 threads; 4x4 tile per thread.
// ---------------------------------------------------------------------------
template<int K, int N, int CG>
__global__ __launch_bounds__(256)
void proj_kernel(const float* __restrict__ in, const float* __restrict__ W,
                 const float* __restrict__ bias, float* __restrict__ out, int M)
{
  constexpr int NP = CG * 4;
  constexpr int RG = 256 / CG;  // active row-groups
  __shared__ __align__(16) float wlds[K][NP];
  __shared__ __align__(16) float blds[NP];
  const int tid = threadIdx.x;
  for (int idx = tid; idx < K * NP; idx += 256) {
    int k = idx / NP, jj = idx - k * NP;
    wlds[k][jj] = (jj < N) ? W[k * N + jj] : 0.0f;
  }
  if (tid < NP) blds[tid] = (tid < N) ? bias[tid] : 0.0f;
  __syncthreads();

  const int c = tid % CG;
  const int rg = tid / CG;
  if (rg >= RG) return;  // no barriers after this point
  const int j0 = c * 4;
  const long row0 = (long)blockIdx.x * (RG * 4) + (long)rg * 4;

  float4 b4 = *reinterpret_cast<const float4*>(&blds[j0]);
  float4 acc[4] = {b4, b4, b4, b4};
  const float* inp[4];
  bool rv[4];
  #pragma unroll
  for (int rr = 0; rr < 4; ++rr) {
    long rowi = row0 + rr;
    rv[rr] = rowi < M;
    inp[rr] = in + (rv[rr] ? rowi : 0) * (long)K;
  }

  int k = 0;
  for (; k + 4 <= K; k += 4) {
    float4 w0 = *reinterpret_cast<const float4*>(&wlds[k + 0][j0]);
    float4 w1 = *reinterpret_cast<const float4*>(&wlds[k + 1][j0]);
    float4 w2 = *reinterpret_cast<const float4*>(&wlds[k + 2][j0]);
    float4 w3 = *reinterpret_cast<const float4*>(&wlds[k + 3][j0]);
    #pragma unroll
    for (int rr = 0; rr < 4; ++rr) {
      float2 i0 = *reinterpret_cast<const float2*>(inp[rr] + k);
      float2 i1 = *reinterpret_cast<const float2*>(inp[rr] + k + 2);
      fma4(acc[rr], i0.x, w0);
      fma4(acc[rr], i0.y, w1);
      fma4(acc[rr], i1.x, w2);
      fma4(acc[rr], i1.y, w3);
    }
  }
  for (; k < K; ++k) {  // K tail (K=78)
    float4 w0 = *reinterpret_cast<const float4*>(&wlds[k][j0]);
    #pragma unroll
    for (int rr = 0; rr < 4; ++rr) fma4(acc[rr], inp[rr][k], w0);
  }

  #pragma unroll
  for (int rr = 0; rr < 4; ++rr) {
    if (!rv[rr]) continue;
    long obase = (row0 + rr) * (long)N + j0;
    if constexpr ((N % 4) == 0) {
      *reinterpret_cast<float4*>(&out[obase]) = acc[rr];
    } else {
      if (j0 + 4 <= N) {
        *reinterpret_cast<float2*>(&out[obase]) = make_float2(acc[rr].x, acc[rr].y);
        *reinterpret_cast<float2*>(&out[obase + 2]) = make_float2(acc[rr].z, acc[rr].w);
      } else {
        float v[4] = {acc[rr].x, acc[rr].y, acc[rr].z, acc[rr].w};
        #pragma unroll
        for (int jj = 0; jj < 4; ++jj)
          if (j0 + jj < N) out[obase + jj] = v[jj];
      }
    }
  }
}

// ---------------------------------------------------------------------------
// rec (H in {16,32,64}): single wave, ROWS = 64/H batch rows per wave.
// h_t = tanh(xw_t + h_{t-1} @ U).  No barriers in loop.  Depth-8 xw prefetch.
// ---------------------------------------------------------------------------
template<int H, int ROWS>
__global__ __launch_bounds__(64, 1)
void rec_kernel(const float* __restrict__ xw, const float* __restrict__ U,
                float* __restrict__ hseq)
{
  constexpr int HP = (H + 3) & ~3;
  constexpr int PF = 8;
  const int tid = threadIdx.x;
  const int r = tid / H;          // row-in-block
  const int j = tid - r * H;      // column
  const int row = blockIdx.x * ROWS + r;

  __shared__ __align__(16) float hlds[ROWS][HP];
  for (int i = tid; i < ROWS * HP; i += 64)
    reinterpret_cast<float*>(hlds)[i] = 0.0f;
  __syncthreads();  // once, pre-loop

  float u[HP];
  #pragma unroll
  for (int kk = 0; kk < HP; ++kk) {
    u[kk] = (kk < H) ? U[kk * H + j] : 0.0f;
    asm volatile("" : "+v"(u[kk]));  // pin in VGPR (no remat / no scratch)
  }

  const float* xwrow = xw + ((size_t)row * TT) * H + j;
  float* hout = hseq + ((size_t)row * TT) * H + j;

  float pf[PF];
  #pragma unroll
  for (int d = 0; d < PF; ++d) pf[d] = xwrow[(size_t)d * H];

  for (int t = 0; t < TT; t += PF) {
    #pragma unroll
    for (int d = 0; d < PF; ++d) {
      float xv = pf[d];
      int tn = t + d + PF;
      tn = (tn < TT) ? tn : (TT - 1);
      pf[d] = xwrow[(size_t)tn * H];  // issued now, consumed 8 steps later

      const float* hb = &hlds[r][0];
      float a0 = xv, a1 = 0.0f, a2 = 0.0f, a3 = 0.0f;
      #pragma unroll
      for (int k4 = 0; k4 < HP / 4; ++k4) {  // broadcast LDS reads
        float4 h4 = *reinterpret_cast<const float4*>(hb + 4 * k4);
        a0 = fmaf(h4.x, u[4 * k4 + 0], a0);
        a1 = fmaf(h4.y, u[4 * k4 + 1], a1);
        a2 = fmaf(h4.z, u[4 * k4 + 2], a2);
        a3 = fmaf(h4.w, u[4 * k4 + 3], a3);
      }
      float hn = tanh_fast((a0 + a1) + (a2 + a3));
      hlds[r][j] = hn;                 // in-order DS: visible to next step's reads
      hout[(size_t)(t + d) * H] = hn;  // fire-and-forget global store
    }
  }
}

// ---------------------------------------------------------------------------
// rec70 (last layer): single wave per batch row.  Lane j owns column j AND
// column 64+j (j<6).  Fused dense(70->5) + softmax via __shfl.  No hseq.
// ---------------------------------------------------------------------------
__global__ __launch_bounds__(64, 1)
void rec70_kernel(const float* __restrict__ xw, const float* __restrict__ U,
                  const float* __restrict__ Wd, const float* __restrict__ bd,
                  float* __restrict__ outp)
{
  constexpr int H = 70, HP = 72, PF = 8;
  const int tid = threadIdx.x;
  const int row = blockIdx.x;
  const int j2 = (tid < 6) ? (64 + tid) : 69;  // clamped 2nd column

  __shared__ __align__(16) float hlds[HP];
  for (int i = tid; i < HP; i += 64) hlds[i] = 0.0f;
  __syncthreads();

  float u[HP], u2[HP];
  #pragma unroll
  for (int kk = 0; kk < HP; ++kk) {
    u[kk]  = (kk < H) ? U[kk * H + tid] : 0.0f;
    u2[kk] = (kk < H && tid < 6) ? U[kk * H + 64 + tid] : 0.0f;
    asm volatile("" : "+v"(u[kk]), "+v"(u2[kk]));
  }

  const float* xwrow = xw + ((size_t)row * TT) * H;
  float pfA[PF], pfB[PF];
  #pragma unroll
  for (int d = 0; d < PF; ++d) {
    pfA[d] = xwrow[(size_t)d * H + tid];
    pfB[d] = xwrow[(size_t)d * H + j2];
  }

  for (int t = 0; t < TT; t += PF) {
    #pragma unroll
    for (int d = 0; d < PF; ++d) {
      float xvA = pfA[d], xvB = pfB[d];
      int tn = t + d + PF;
      tn = (tn < TT) ? tn : (TT - 1);
      pfA[d] = xwrow[(size_t)tn * H + tid];
      pfB[d] = xwrow[(size_t)tn * H + j2];

      float a0 = xvA, a1 = 0.0f, a2 = 0.0f, a3 = 0.0f;
      float b0 = xvB, b1 = 0.0f, b2 = 0.0f, b3 = 0.0f;
      #pragma unroll
      for (int k4 = 0; k4 < HP / 4; ++k4) {
        float4 h4 = *reinterpret_cast<const float4*>(&hlds[4 * k4]);
        a0 = fmaf(h4.x, u[4 * k4 + 0], a0);
        a1 = fmaf(h4.y, u[4 * k4 + 1], a1);
        a2 = fmaf(h4.z, u[4 * k4 + 2], a2);
        a3 = fmaf(h4.w, u[4 * k4 + 3], a3);
        b0 = fmaf(h4.x, u2[4 * k4 + 0], b0);
        b1 = fmaf(h4.y, u2[4 * k4 + 1], b1);
        b2 = fmaf(h4.z, u2[4 * k4 + 2], b2);
        b3 = fmaf(h4.w, u2[4 * k4 + 3], b3);
      }
      float hnA = tanh_fast((a0 + a1) + (a2 + a3));
      float hnB = tanh_fast((b0 + b1) + (b2 + b3));
      hlds[tid] = hnA;
      if (tid < 6) hlds[64 + tid] = hnB;  // exec-masked 2nd write
    }
  }

  // dense (70->5) + softmax on final h (in hlds), all within the wave
  float l = 0.0f;
  if (tid < 5) {
    l = bd[tid];
    #pragma unroll
    for (int kk = 0; kk < H; ++kk)
      l = fmaf(hlds[kk], Wd[kk * 5 + tid], l);
  }
  float l0 = __shfl(l, 0), l1 = __shfl(l, 1), l2 = __shfl(l, 2),
        l3 = __shfl(l, 3), l4 = __shfl(l, 4);
  float m = fmaxf(fmaxf(fmaxf(l0, l1), fmaxf(l2, l3)), l4);
  float s = __expf(l0 - m) + __expf(l1 - m) + __expf(l2 - m) +
            __expf(l3 - m) + __expf(l4 - m);
  if (tid < 5)
    outp[(size_t)row * 5 + tid] = __expf(l - m) / s;
}

extern "C" void kernel_launch(void* const* d_in, const int* in_sizes, int n_in,
                              void* d_out, int out_size, void* d_ws, size_t ws_size,
                              hipStream_t stream)
{
  const float* x  = (const float*)d_in[0];
  const float* W0 = (const float*)d_in[1];
  const float* U0 = (const float*)d_in[2];
  const float* b0 = (const float*)d_in[3];
  const float* W1 = (const float*)d_in[4];
  const float* U1 = (const float*)d_in[5];
  const float* b1 = (const float*)d_in[6];
  const float* W2 = (const float*)d_in[7];
  const float* U2 = (const float*)d_in[8];
  const float* b2 = (const float*)d_in[9];
  const float* W3 = (const float*)d_in[10];
  const float* U3 = (const float*)d_in[11];
  const float* b3 = (const float*)d_in[12];
  const float* Wd = (const float*)d_in[13];
  const float* bd = (const float*)d_in[14];
  float* outp = (float*)d_out;

  // ws ping-pong: A holds xw (max 73,400,320 B), Bv holds h sequences (max 67,108,864 B)
  float* A  = (float*)d_ws;
  float* Bv = (float*)((char*)d_ws + 73400320);

  const int M = M_TOTAL;

  // xw0 = x @ W0 + b0                    [M,78]x[78,16]
  proj_kernel<78, 16, 4><<<M / 256, 256, 0, stream>>>(x, W0, b0, A, M);
  // h0 sequence                          H=16, 4 rows per single-wave block
  rec_kernel<16, 4><<<BB / 4, 64, 0, stream>>>(A, U0, Bv);
  // xw1 = h0 @ W1 + b1                   [M,16]x[16,32]
  proj_kernel<16, 32, 8><<<M / 128, 256, 0, stream>>>(Bv, W1, b1, A, M);
  // h1                                   H=32, 2 rows per wave
  rec_kernel<32, 2><<<BB / 2, 64, 0, stream>>>(A, U1, Bv);
  // xw2 = h1 @ W2 + b2                   [M,32]x[32,64]
  proj_kernel<32, 64, 16><<<M / 64, 256, 0, stream>>>(Bv, W2, b2, A, M);
  // h2                                   H=64, 1 row per wave
  rec_kernel<64, 1><<<BB, 64, 0, stream>>>(A, U2, Bv);
  // xw3 = h2 @ W3 + b3                   [M,64]x[64,70]
  proj_kernel<64, 70, 18><<<(M + 55) / 56, 256, 0, stream>>>(Bv, W3, b3, A, M);
  // final scan H=70 single-wave dual-column + dense + softmax
  rec70_kernel<<<BB, 64, 0, stream>>>(A, U3, Wd, bd, outp);
}